// Round 1
// baseline (1188.197 us; speedup 1.0000x reference)
//
#include <hip/hip_runtime.h>
#include <math.h>

#define BN 8
#define CIN 3
#define HH 512
#define WW 512
#define KK 9
#define OC 3
#define OFFC 27   // 18 offset channels + 9 mask channels

__global__ __launch_bounds__(256) void deform_fused_kernel(
    const float* __restrict__ x,
    const float* __restrict__ w_off,
    const float* __restrict__ b_off,
    const float* __restrict__ w_def,
    const float* __restrict__ b_def,
    float* __restrict__ out)
{
    __shared__ float s_woff[OFFC * CIN * KK];  // 729 floats
    __shared__ float s_boff[OFFC];
    __shared__ float s_wdef[OC * CIN * KK];    // 81 floats
    __shared__ float s_bdef[OC];

    for (int i = threadIdx.x; i < OFFC * CIN * KK; i += blockDim.x) s_woff[i] = w_off[i];
    if (threadIdx.x < OFFC)          s_boff[threadIdx.x] = b_off[threadIdx.x];
    if (threadIdx.x < OC * CIN * KK) s_wdef[threadIdx.x] = w_def[threadIdx.x];
    if (threadIdx.x < OC)            s_bdef[threadIdx.x] = b_def[threadIdx.x];
    __syncthreads();

    const int w = blockIdx.x * blockDim.x + threadIdx.x;
    const int h = blockIdx.y;
    const int b = blockIdx.z;
    if (w >= WW) return;

    const float* xb = x + (size_t)b * CIN * HH * WW;

    // ---- 3x3x3 zero-padded patch ----
    float patch[CIN][KK];
    #pragma unroll
    for (int c = 0; c < CIN; ++c) {
        const float* xp = xb + (size_t)c * HH * WW;
        #pragma unroll
        for (int t = 0; t < KK; ++t) {
            const int yy = h + t / 3 - 1;
            const int xx = w + t % 3 - 1;
            const bool in = (yy >= 0) & (yy < HH) & (xx >= 0) & (xx < WW);
            patch[c][t] = in ? xp[yy * WW + xx] : 0.0f;
        }
    }

    // ---- offset conv: 27 output channels ----
    float ow[OFFC];
    #pragma unroll
    for (int o = 0; o < OFFC; ++o) {
        float acc = s_boff[o];
        #pragma unroll
        for (int c = 0; c < CIN; ++c) {
            #pragma unroll
            for (int t = 0; t < KK; ++t) {
                acc = fmaf(s_woff[o * (CIN * KK) + c * KK + t], patch[c][t], acc);
            }
        }
        ow[o] = acc;
    }

    // ---- deformable sampling + output contraction ----
    float acc0 = s_bdef[0];
    float acc1 = s_bdef[1];
    float acc2 = s_bdef[2];

    #pragma unroll
    for (int k = 0; k < KK; ++k) {
        const float offy = ow[2 * k];
        const float offx = ow[2 * k + 1];
        const float m = 1.0f / (1.0f + expf(-ow[18 + k]));

        const float py = (float)h + (float)(k / 3 - 1) + offy;
        const float px = (float)w + (float)(k % 3 - 1) + offx;
        const float y0f = floorf(py);
        const float x0f = floorf(px);
        const float dy = py - y0f;
        const float dx = px - x0f;
        const int y0 = (int)y0f;
        const int x0 = (int)x0f;

        const float w00 = (1.0f - dy) * (1.0f - dx);
        const float w01 = (1.0f - dy) * dx;
        const float w10 = dy * (1.0f - dx);
        const float w11 = dy * dx;

        const bool vy0 = (y0 >= 0)     & (y0 < HH);
        const bool vy1 = (y0 + 1 >= 0) & (y0 + 1 < HH);
        const bool vx0 = (x0 >= 0)     & (x0 < WW);
        const bool vx1 = (x0 + 1 >= 0) & (x0 + 1 < WW);

        const int yc0 = min(max(y0, 0), HH - 1);
        const int yc1 = min(max(y0 + 1, 0), HH - 1);
        const int xc0 = min(max(x0, 0), WW - 1);
        const int xc1 = min(max(x0 + 1, 0), WW - 1);

        #pragma unroll
        for (int c = 0; c < CIN; ++c) {
            const float* xp = xb + (size_t)c * HH * WW;
            const float v00 = (vy0 & vx0) ? xp[yc0 * WW + xc0] : 0.0f;
            const float v01 = (vy0 & vx1) ? xp[yc0 * WW + xc1] : 0.0f;
            const float v10 = (vy1 & vx0) ? xp[yc1 * WW + xc0] : 0.0f;
            const float v11 = (vy1 & vx1) ? xp[yc1 * WW + xc1] : 0.0f;

            float val = v00 * w00 + v01 * w01 + v10 * w10 + v11 * w11;
            val *= m;

            acc0 = fmaf(s_wdef[0 * (CIN * KK) + c * KK + k], val, acc0);
            acc1 = fmaf(s_wdef[1 * (CIN * KK) + c * KK + k], val, acc1);
            acc2 = fmaf(s_wdef[2 * (CIN * KK) + c * KK + k], val, acc2);
        }
    }

    const size_t plane = (size_t)HH * WW;
    const size_t base = (size_t)b * OC * plane + (size_t)h * WW + w;
    out[base]             = acc0;
    out[base + plane]     = acc1;
    out[base + 2 * plane] = acc2;
}

extern "C" void kernel_launch(void* const* d_in, const int* in_sizes, int n_in,
                              void* d_out, int out_size, void* d_ws, size_t ws_size,
                              hipStream_t stream) {
    const float* x     = (const float*)d_in[0];
    const float* w_off = (const float*)d_in[1];
    const float* b_off = (const float*)d_in[2];
    const float* w_def = (const float*)d_in[3];
    const float* b_def = (const float*)d_in[4];
    float* out = (float*)d_out;

    dim3 block(256, 1, 1);
    dim3 grid(WW / 256, HH, BN);  // (2, 512, 8)
    deform_fused_kernel<<<grid, block, 0, stream>>>(x, w_off, b_off, w_def, b_def, out);
}

// Round 2
// 222.300 us; speedup vs baseline: 5.3450x; 5.3450x over previous
//
#include <hip/hip_runtime.h>
#include <math.h>

#define BN 8
#define CIN 3
#define HH 512
#define WW 512
#define KK 9
#define OC 3
#define OFFC 27   // 18 offset channels + 9 mask channels
#define PATCH 27  // CIN*KK

__global__ __launch_bounds__(256) void deform_fused_kernel(
    const float* __restrict__ x,
    const float* __restrict__ w_off,
    const float* __restrict__ b_off,
    const float* __restrict__ w_def,
    const float* __restrict__ b_def,
    float* __restrict__ out)
{
    __shared__ float s_woff[OFFC * PATCH];  // 729 floats, layout [o][c][t]
    __shared__ float s_boff[OFFC];
    __shared__ float s_wdef[OC * PATCH];    // 81 floats, layout [o][c][k]
    __shared__ float s_bdef[OC];

    for (int i = threadIdx.x; i < OFFC * PATCH; i += blockDim.x) s_woff[i] = w_off[i];
    if (threadIdx.x < OFFC)       s_boff[threadIdx.x] = b_off[threadIdx.x];
    if (threadIdx.x < OC * PATCH) s_wdef[threadIdx.x] = w_def[threadIdx.x];
    if (threadIdx.x < OC)         s_bdef[threadIdx.x] = b_def[threadIdx.x];
    __syncthreads();

    const int w = blockIdx.x * blockDim.x + threadIdx.x;
    const int h = blockIdx.y;
    const int b = blockIdx.z;
    if (w >= WW) return;

    const float* xb = x + (size_t)b * CIN * HH * WW;

    // ---- 3x3x3 zero-padded patch, flat index = c*9 + t (matches weight layout) ----
    float patch[PATCH];
    #pragma unroll
    for (int c = 0; c < CIN; ++c) {
        const float* xp = xb + (size_t)c * HH * WW;
        #pragma unroll
        for (int t = 0; t < KK; ++t) {
            const int yy = h + t / 3 - 1;
            const int xx = w + t % 3 - 1;
            const bool in = (yy >= 0) & (yy < HH) & (xx >= 0) & (xx < WW);
            patch[c * KK + t] = in ? xp[yy * WW + xx] : 0.0f;
        }
    }

    float acc0 = s_bdef[0];
    float acc1 = s_bdef[1];
    float acc2 = s_bdef[2];

    // ---- per-tap: offset-conv channels (2k, 2k+1, 18+k), bilinear sample, contract ----
    #pragma unroll 1
    for (int k = 0; k < KK; ++k) {
        float oy = s_boff[2 * k];
        float ox = s_boff[2 * k + 1];
        float om = s_boff[18 + k];
        const float* wy = &s_woff[(2 * k) * PATCH];
        const float* wx = &s_woff[(2 * k + 1) * PATCH];
        const float* wm = &s_woff[(18 + k) * PATCH];
        #pragma unroll
        for (int i = 0; i < PATCH; ++i) {
            const float p = patch[i];
            oy = fmaf(wy[i], p, oy);
            ox = fmaf(wx[i], p, ox);
            om = fmaf(wm[i], p, om);
        }

        const float m = 1.0f / (1.0f + __expf(-om));

        const float py = (float)h + (float)(k / 3 - 1) + oy;
        const float px = (float)w + (float)(k % 3 - 1) + ox;
        const float y0f = floorf(py);
        const float x0f = floorf(px);
        const float dy = py - y0f;
        const float dx = px - x0f;
        const int y0 = (int)y0f;
        const int x0 = (int)x0f;

        const float w00 = (1.0f - dy) * (1.0f - dx);
        const float w01 = (1.0f - dy) * dx;
        const float w10 = dy * (1.0f - dx);
        const float w11 = dy * dx;

        const bool vy0 = (y0 >= 0)     & (y0 < HH);
        const bool vy1 = (y0 + 1 >= 0) & (y0 + 1 < HH);
        const bool vx0 = (x0 >= 0)     & (x0 < WW);
        const bool vx1 = (x0 + 1 >= 0) & (x0 + 1 < WW);

        const int yc0 = min(max(y0, 0), HH - 1);
        const int yc1 = min(max(y0 + 1, 0), HH - 1);
        const int xc0 = min(max(x0, 0), WW - 1);
        const int xc1 = min(max(x0 + 1, 0), WW - 1);

        #pragma unroll
        for (int c = 0; c < CIN; ++c) {
            const float* xp = xb + (size_t)c * HH * WW;
            const float v00 = (vy0 & vx0) ? xp[yc0 * WW + xc0] : 0.0f;
            const float v01 = (vy0 & vx1) ? xp[yc0 * WW + xc1] : 0.0f;
            const float v10 = (vy1 & vx0) ? xp[yc1 * WW + xc0] : 0.0f;
            const float v11 = (vy1 & vx1) ? xp[yc1 * WW + xc1] : 0.0f;

            float val = v00 * w00 + v01 * w01 + v10 * w10 + v11 * w11;
            val *= m;

            acc0 = fmaf(s_wdef[0 * PATCH + c * KK + k], val, acc0);
            acc1 = fmaf(s_wdef[1 * PATCH + c * KK + k], val, acc1);
            acc2 = fmaf(s_wdef[2 * PATCH + c * KK + k], val, acc2);
        }
    }

    const size_t plane = (size_t)HH * WW;
    const size_t base = (size_t)b * OC * plane + (size_t)h * WW + w;
    out[base]             = acc0;
    out[base + plane]     = acc1;
    out[base + 2 * plane] = acc2;
}

extern "C" void kernel_launch(void* const* d_in, const int* in_sizes, int n_in,
                              void* d_out, int out_size, void* d_ws, size_t ws_size,
                              hipStream_t stream) {
    const float* x     = (const float*)d_in[0];
    const float* w_off = (const float*)d_in[1];
    const float* b_off = (const float*)d_in[2];
    const float* w_def = (const float*)d_in[3];
    const float* b_def = (const float*)d_in[4];
    float* out = (float*)d_out;

    dim3 block(256, 1, 1);
    dim3 grid(WW / 256, HH, BN);  // (2, 512, 8)
    deform_fused_kernel<<<grid, block, 0, stream>>>(x, w_off, b_off, w_def, b_def, out);
}